// Round 1
// baseline (173.661 us; speedup 1.0000x reference)
//
#include <hip/hip_runtime.h>
#include <cfloat>
#include <cstdint>

// Problem constants (SHAPE=(96,128,128), B=2, C=32, two maxpool(K3,S2,P1) layers)
// Composed pooling: window 7, stride 4, pad 3.
#define B_   2
#define OD   24
#define OH   32
#define OW   32
#define NC   32

__device__ __forceinline__ void atomicMaxFloat(float* addr, float value) {
    // Correct for all non-NaN floats: signed-int compare works for +floats,
    // unsigned-int compare is reversed for -floats.
    if (!signbit(value)) {
        atomicMax(reinterpret_cast<int*>(addr), __float_as_int(value));
    } else {
        atomicMin(reinterpret_cast<unsigned int*>(addr), __float_as_uint(value));
    }
}

__global__ void k_init(float* __restrict__ out, int n) {
    const int stride = gridDim.x * blockDim.x;
    const int n4 = n >> 2;
    const float4 v = make_float4(-FLT_MAX, -FLT_MAX, -FLT_MAX, -FLT_MAX);
    for (int i = blockIdx.x * blockDim.x + threadIdx.x; i < n4; i += stride)
        reinterpret_cast<float4*>(out)[i] = v;
    // tail (out_size is divisible by 4 here, but keep it safe)
    for (int i = (n & ~3) + blockIdx.x * blockDim.x + threadIdx.x; i < n; i += stride)
        out[i] = -FLT_MAX;
}

__global__ void k_scatter(const float* __restrict__ feat,
                          const int* __restrict__ coors,
                          float* __restrict__ out, int N) {
    int t = blockIdx.x * blockDim.x + threadIdx.x;
    int i = t >> 5;        // point index
    int c = t & 31;        // channel
    if (i >= N) return;

    const int b = coors[4 * i + 0];
    const int z = coors[4 * i + 1];
    const int y = coors[4 * i + 2];
    const int x = coors[4 * i + 3];
    const float f = feat[i * NC + c];   // coalesced across the 32-lane group

    // output cells whose 7-wide stride-4 window covers this input site:
    // 4o-3 <= z <= 4o+3  =>  o in [ceil((z-3)/4), floor((z+3)/4)] = [z>>2, (z+3)>>2]
    const int zlo = z >> 2, zhi = min((z + 3) >> 2, OD - 1);
    const int ylo = y >> 2, yhi = min((y + 3) >> 2, OH - 1);
    const int xlo = x >> 2, xhi = min((x + 3) >> 2, OW - 1);

    for (int oz = zlo; oz <= zhi; ++oz) {
        for (int oy = ylo; oy <= yhi; ++oy) {
            for (int ox = xlo; ox <= xhi; ++ox) {
                const int idx = ((((b * OD + oz) * OH + oy) * OW + ox) * NC) + c;
                atomicMaxFloat(&out[idx], f);
            }
        }
    }
}

__global__ void k_finalize(float* __restrict__ out, int n) {
    const int stride = gridDim.x * blockDim.x;
    const int n4 = n >> 2;
    for (int i = blockIdx.x * blockDim.x + threadIdx.x; i < n4; i += stride) {
        float4 v = reinterpret_cast<float4*>(out)[i];
        if (__float_as_uint(v.x) == 0xFF7FFFFFu) v.x = 0.0f;
        if (__float_as_uint(v.y) == 0xFF7FFFFFu) v.y = 0.0f;
        if (__float_as_uint(v.z) == 0xFF7FFFFFu) v.z = 0.0f;
        if (__float_as_uint(v.w) == 0xFF7FFFFFu) v.w = 0.0f;
        reinterpret_cast<float4*>(out)[i] = v;
    }
    for (int i = (n & ~3) + blockIdx.x * blockDim.x + threadIdx.x; i < n; i += stride) {
        float v = out[i];
        if (__float_as_uint(v) == 0xFF7FFFFFu) out[i] = 0.0f;
    }
}

extern "C" void kernel_launch(void* const* d_in, const int* in_sizes, int n_in,
                              void* d_out, int out_size, void* d_ws, size_t ws_size,
                              hipStream_t stream) {
    const float* feat  = (const float*)d_in[0];
    const int*   coors = (const int*)d_in[1];
    const int N = in_sizes[0] / NC;       // 200000
    float* out = (float*)d_out;           // out_size = 2*24*32*32*32 = 1572864

    // 1) init output to -FLT_MAX sentinel
    {
        int blocks = min((out_size / 4 + 255) / 256, 2048);
        k_init<<<blocks, 256, 0, stream>>>(out, out_size);
    }
    // 2) scatter-max: one thread per (point, channel)
    {
        int total = N * NC;
        int blocks = (total + 255) / 256;
        k_scatter<<<blocks, 256, 0, stream>>>(feat, coors, out, N);
    }
    // 3) untouched sentinel cells -> 0
    {
        int blocks = min((out_size / 4 + 255) / 256, 2048);
        k_finalize<<<blocks, 256, 0, stream>>>(out, out_size);
    }
}

// Round 2
// 128.572 us; speedup vs baseline: 1.3507x; 1.3507x over previous
//
#include <hip/hip_runtime.h>
#include <cfloat>
#include <cstdint>

// Problem constants (SHAPE=(96,128,128), B=2, C=32, two maxpool(K3,S2,P1) layers)
// Composed pooling: window 7, stride 4, pad 3. Output grid 2 x 24 x 32 x 32 x 32.
#define B_    2
#define OD    24
#define OH    32
#define OW    32
#define NC    32
#define NBINS (B_ * OD * OH * OW)   // 49152 == number of output spatial cells
#define SCAN_T 1024
#define CHUNK  (NBINS / SCAN_T)     // 48 exactly

// ---------------- binning ----------------

__global__ void k_hist(const int* __restrict__ coors, int* __restrict__ counts, int N) {
    int i = blockIdx.x * blockDim.x + threadIdx.x;
    if (i >= N) return;
    int4 cc = reinterpret_cast<const int4*>(coors)[i];   // b, z, y, x
    int bin = (((cc.x * OD + (cc.y >> 2)) * OH + (cc.z >> 2)) * OW + (cc.w >> 2));
    atomicAdd(&counts[bin], 1);
}

__global__ void k_scan(const int* __restrict__ counts,
                       int* __restrict__ offsets,
                       int* __restrict__ cursor) {
    __shared__ int lds[SCAN_T];
    int t = threadIdx.x;
    int base = t * CHUNK;
    int s = 0;
#pragma unroll
    for (int k = 0; k < CHUNK; ++k) s += counts[base + k];
    lds[t] = s;
    __syncthreads();
    // Hillis-Steele inclusive scan over 1024 partials
    for (int d = 1; d < SCAN_T; d <<= 1) {
        int v = (t >= d) ? lds[t - d] : 0;
        __syncthreads();
        lds[t] += v;
        __syncthreads();
    }
    int excl = (t == 0) ? 0 : lds[t - 1];
    for (int k = 0; k < CHUNK; ++k) {
        int i = base + k;
        offsets[i] = excl;
        cursor[i]  = excl;
        excl += counts[i];
    }
}

__global__ void k_place(const int* __restrict__ coors, int* __restrict__ cursor,
                        int* __restrict__ records, int N) {
    int i = blockIdx.x * blockDim.x + threadIdx.x;
    if (i >= N) return;
    int4 cc = reinterpret_cast<const int4*>(coors)[i];
    int bin = (((cc.x * OD + (cc.y >> 2)) * OH + (cc.z >> 2)) * OW + (cc.w >> 2));
    int pos = atomicAdd(&cursor[bin], 1);
    // record: point index in high bits, low 2 bits of (z,y,x) for the accept test
    records[pos] = (i << 6) | (cc.y & 3) | ((cc.z & 3) << 2) | ((cc.w & 3) << 4);
}

// ---------------- gather ----------------
// One wave (64 lanes) per output cell. lanes 0-31 = channels of candidate 2j,
// lanes 32-63 = channels of candidate 2j+1; final fmax across halves.
// A point in neighbor bin (oz-1) qualifies iff (z&3)!=0 (i.e. z >= 4*oz-3);
// a point in bin oz always qualifies (z <= 4*oz+3 within the bin).

__global__ void k_gather(const float* __restrict__ feat,
                         const int* __restrict__ offsets,
                         const int* __restrict__ counts,
                         const int* __restrict__ records,
                         float* __restrict__ out) {
    int tid  = blockIdx.x * blockDim.x + threadIdx.x;
    int wid  = tid >> 6;             // output cell id
    int lane = threadIdx.x & 63;
    int h    = lane >> 5;            // half-wave (candidate parity)
    int c    = lane & 31;            // channel

    int ox  = wid & (OW - 1);
    int oy  = (wid >> 5) & (OH - 1);
    int bzc = wid >> 10;             // b*OD + oz, in [0, 48)
    int b   = bzc / OD;
    int oz  = bzc - b * OD;

    float m  = -FLT_MAX;
    int   any = 0;

#pragma unroll
    for (int k = 0; k < 8; ++k) {
        const int lz = k & 1, ly = (k >> 1) & 1, lx = (k >> 2) & 1;
        int z2 = oz - lz, y2 = oy - ly, x2 = ox - lx;
        if ((z2 | y2 | x2) < 0) continue;            // out of grid (lower side only)
        int bin = ((b * OD + z2) * OH + y2) * OW + x2;
        int off = offsets[bin];
        int cnt = counts[bin];
        for (int j = h; j < cnt; j += 2) {
            int rec = records[off + j];
            bool ok = (!lz || (rec & 3)) && (!ly || (rec & 12)) && (!lx || (rec & 48));
            if (ok) {
                float f = feat[(rec >> 6) * NC + c];
                m = fmaxf(m, f);
                any = 1;
            }
        }
    }

    // combine the two half-waves
    m   = fmaxf(m, __shfl_xor(m, 32, 64));
    any |= __shfl_xor(any, 32, 64);
    if (h == 0) {
        out[wid * NC + c] = any ? m : 0.0f;
    }
}

// ---------------- launch ----------------

extern "C" void kernel_launch(void* const* d_in, const int* in_sizes, int n_in,
                              void* d_out, int out_size, void* d_ws, size_t ws_size,
                              hipStream_t stream) {
    const float* feat  = (const float*)d_in[0];
    const int*   coors = (const int*)d_in[1];
    const int N = in_sizes[0] / NC;          // 200000
    float* out = (float*)d_out;              // 2*24*32*32*32 = 1572864 floats

    int* counts  = (int*)d_ws;               // NBINS
    int* offsets = counts + NBINS;           // NBINS
    int* cursor  = offsets + NBINS;          // NBINS
    int* records = cursor + NBINS;           // N

    hipMemsetAsync(counts, 0, NBINS * sizeof(int), stream);
    k_hist <<<(N + 255) / 256, 256, 0, stream>>>(coors, counts, N);
    k_scan <<<1, SCAN_T, 0, stream>>>(counts, offsets, cursor);
    k_place<<<(N + 255) / 256, 256, 0, stream>>>(coors, cursor, records, N);
    k_gather<<<(NBINS * 64) / 256, 256, 0, stream>>>(feat, offsets, counts, records, out);
}

// Round 3
// 101.723 us; speedup vs baseline: 1.7072x; 1.2639x over previous
//
#include <hip/hip_runtime.h>
#include <cfloat>
#include <cstdint>

// Problem constants (SHAPE=(96,128,128), B=2, C=32, two maxpool(K3,S2,P1) layers)
// Composed pooling: window 7, stride 4, pad 3. Output grid 2 x 24 x 32 x 32 x 32.
#define B_    2
#define OD    24
#define OH    32
#define OW    32
#define NC    32
#define NBINS (B_ * OD * OH * OW)   // 49152
#define SCAN_T 1024
#define CHUNK  (NBINS / SCAN_T)     // 48

// ws layout (ints):
//   counts  [NBINS]
//   binfo   [NBINS] int2   (offset, count)
//   cursor  [NBINS]
//   records [N + 8]        (8 slack entries; reads there are mask-discarded)

// ---------------- binning ----------------

__global__ void k_hist(const int* __restrict__ coors, int* __restrict__ counts, int N) {
    int i = blockIdx.x * blockDim.x + threadIdx.x;
    if (i >= N) return;
    int4 cc = reinterpret_cast<const int4*>(coors)[i];   // b, z, y, x
    int bin = (((cc.x * OD + (cc.y >> 2)) * OH + (cc.z >> 2)) * OW + (cc.w >> 2));
    atomicAdd(&counts[bin], 1);
}

__global__ void k_scan(const int* __restrict__ counts,
                       int2* __restrict__ binfo,
                       int* __restrict__ cursor) {
    __shared__ int lds[SCAN_T];
    int t = threadIdx.x;
    int base = t * CHUNK;
    int s = 0;
#pragma unroll
    for (int k = 0; k < CHUNK; ++k) s += counts[base + k];
    lds[t] = s;
    __syncthreads();
    for (int d = 1; d < SCAN_T; d <<= 1) {
        int v = (t >= d) ? lds[t - d] : 0;
        __syncthreads();
        lds[t] += v;
        __syncthreads();
    }
    int excl = (t == 0) ? 0 : lds[t - 1];
    for (int k = 0; k < CHUNK; ++k) {
        int i = base + k;
        int c = counts[i];
        binfo[i] = make_int2(excl, c);
        cursor[i] = excl;
        excl += c;
    }
}

__global__ void k_place(const int* __restrict__ coors, int* __restrict__ cursor,
                        int* __restrict__ records, int N) {
    int i = blockIdx.x * blockDim.x + threadIdx.x;
    if (i >= N) return;
    int4 cc = reinterpret_cast<const int4*>(coors)[i];
    int bin = (((cc.x * OD + (cc.y >> 2)) * OH + (cc.z >> 2)) * OW + (cc.w >> 2));
    int pos = atomicAdd(&cursor[bin], 1);
    // record: point index high bits; low 2 bits of (z,y,x) for the accept test
    records[pos] = (i << 6) | (cc.y & 3) | ((cc.z & 3) << 2) | ((cc.w & 3) << 4);
}

// ---------------- gather ----------------
// One wave per output cell. Lane = (candidate slot q = lane>>3, channel quad cq = lane&7).
// All 8 bins' binfo loads issue in parallel, then 8 record loads, then 8
// predicated float4 feature loads: chain depth 3 instead of ~16 serial rounds.

__global__ __launch_bounds__(256) void k_gather(const float4* __restrict__ feat4,
                                                const int2* __restrict__ binfo,
                                                const int* __restrict__ records,
                                                float4* __restrict__ out4, int N) {
    int tid  = blockIdx.x * blockDim.x + threadIdx.x;
    int wid  = tid >> 6;             // output cell id
    int lane = threadIdx.x & 63;
    int q    = lane >> 3;            // candidate slot 0..7
    int cq   = lane & 7;             // channel quad 0..7

    int ox  = wid & (OW - 1);
    int oy  = (wid >> 5) & (OH - 1);
    int bzc = wid >> 10;             // b*OD + oz, in [0, 48)
    int b   = (bzc >= OD) ? 1 : 0;
    int oz  = bzc - b * OD;

    // level 1: bin descriptors (8 independent loads)
    int2 bi[8];
#pragma unroll
    for (int k = 0; k < 8; ++k) {
        const int lz = k & 1, ly = (k >> 1) & 1, lx = (k >> 2) & 1;
        int z2 = oz - lz, y2 = oy - ly, x2 = ox - lx;
        bool okbin = ((z2 | y2 | x2) >= 0);
        int bin = ((b * OD + z2) * OH + y2) * OW + x2;
        int2 v = binfo[okbin ? bin : 0];
        if (!okbin) { v.x = N; v.y = 0; }
        bi[k] = v;
    }

    // level 2: records (8 independent loads; masked lanes clamp to slot 0,
    // empty bins read the slack region past records[N] and are mask-discarded)
    int recs[8];
#pragma unroll
    for (int k = 0; k < 8; ++k) {
        int j = (q < bi[k].y) ? q : 0;
        recs[k] = records[bi[k].x + j];
    }

    // level 3: features (8 independent predicated float4 loads) + accumulate
    float4 m = make_float4(-FLT_MAX, -FLT_MAX, -FLT_MAX, -FLT_MAX);
    int any = 0;
#pragma unroll
    for (int k = 0; k < 8; ++k) {
        int rec = recs[k];
        bool ok = (q < bi[k].y);
        if (k & 1) ok = ok && ((rec & 3)  != 0);
        if (k & 2) ok = ok && ((rec & 12) != 0);
        if (k & 4) ok = ok && ((rec & 48) != 0);
        if (ok) {
            float4 f = feat4[(rec >> 6) * (NC / 4) + cq];
            m.x = fmaxf(m.x, f.x); m.y = fmaxf(m.y, f.y);
            m.z = fmaxf(m.z, f.z); m.w = fmaxf(m.w, f.w);
            any = 1;
        }
    }

    // rare slow path: bins with more than 8 candidates (wave-uniform counts)
#pragma unroll
    for (int k = 0; k < 8; ++k) {
        for (int j0 = 8; j0 < bi[k].y; j0 += 8) {
            int j = j0 + q;
            bool ok = (j < bi[k].y);
            int rec = records[bi[k].x + (ok ? j : 0)];
            if (k & 1) ok = ok && ((rec & 3)  != 0);
            if (k & 2) ok = ok && ((rec & 12) != 0);
            if (k & 4) ok = ok && ((rec & 48) != 0);
            if (ok) {
                float4 f = feat4[(rec >> 6) * (NC / 4) + cq];
                m.x = fmaxf(m.x, f.x); m.y = fmaxf(m.y, f.y);
                m.z = fmaxf(m.z, f.z); m.w = fmaxf(m.w, f.w);
                any = 1;
            }
        }
    }

    // reduce across the 8 candidate slots (lanes differing in bits 3..5)
#pragma unroll
    for (int s = 8; s < 64; s <<= 1) {
        m.x = fmaxf(m.x, __shfl_xor(m.x, s, 64));
        m.y = fmaxf(m.y, __shfl_xor(m.y, s, 64));
        m.z = fmaxf(m.z, __shfl_xor(m.z, s, 64));
        m.w = fmaxf(m.w, __shfl_xor(m.w, s, 64));
    }
    bool active = (__ballot(any) != 0ULL);   // wave-uniform

    if (q == 0) {   // lanes 0..7 write the 32-channel row (128 B)
        float4 z4 = make_float4(0.f, 0.f, 0.f, 0.f);
        out4[wid * (NC / 4) + cq] = active ? m : z4;
    }
}

// ---------------- launch ----------------

extern "C" void kernel_launch(void* const* d_in, const int* in_sizes, int n_in,
                              void* d_out, int out_size, void* d_ws, size_t ws_size,
                              hipStream_t stream) {
    const float* feat  = (const float*)d_in[0];
    const int*   coors = (const int*)d_in[1];
    const int N = in_sizes[0] / NC;          // 200000
    float* out = (float*)d_out;              // 1572864 floats

    int*  counts  = (int*)d_ws;              // NBINS
    int2* binfo   = (int2*)(counts + NBINS); // NBINS int2
    int*  cursor  = (int*)(binfo + NBINS);   // NBINS
    int*  records = cursor + NBINS;          // N + 8 (slack)

    hipMemsetAsync(counts, 0, NBINS * sizeof(int), stream);
    k_hist <<<(N + 255) / 256, 256, 0, stream>>>(coors, counts, N);
    k_scan <<<1, SCAN_T, 0, stream>>>(counts, binfo, cursor);
    k_place<<<(N + 255) / 256, 256, 0, stream>>>(coors, cursor, records, N);
    k_gather<<<(NBINS * 64) / 256, 256, 0, stream>>>(
        (const float4*)feat, (const int2*)binfo, records, (float4*)out, N);
}

// Round 4
// 68.435 us; speedup vs baseline: 2.5376x; 1.4864x over previous
//
#include <hip/hip_runtime.h>
#include <cfloat>
#include <cstdint>

// Problem constants (SHAPE=(96,128,128), B=2, C=32, two maxpool(K3,S2,P1) layers)
// Composed pooling: window 7, stride 4, pad 3. Output grid 2 x 24 x 32 x 32 x 32.
#define B_    2
#define OD    24
#define OH    32
#define OW    32
#define NC    32
#define NBINS (B_ * OD * OH * OW)   // 49152
#define CAP   16                    // slots per bin (E[count]=4.07 Poisson)
#define OVF_CAP 200000
#define SCAN_T 1024
#define CHUNK  (NBINS / SCAN_T)

// ================= fast path: fixed-capacity bins (no scan, no place) =======
// ws layout (ints): counts[NBINS] | ovf_n[1] pad[7] | records[NBINS*CAP] | ovf[2*OVF_CAP]

__global__ __launch_bounds__(256) void k_bin(const int* __restrict__ coors,
                                             int* __restrict__ counts,
                                             int* __restrict__ records,
                                             int* __restrict__ ovf_n,
                                             int2* __restrict__ ovf, int N) {
    int i = blockIdx.x * blockDim.x + threadIdx.x;
    if (i >= N) return;
    int4 cc = reinterpret_cast<const int4*>(coors)[i];   // b, z, y, x
    int bin = (((cc.x * OD + (cc.y >> 2)) * OH + (cc.z >> 2)) * OW + (cc.w >> 2));
    // neighbor-qualification mask: bit k (k = lz + 2*ly + 4*lx) says this point
    // qualifies for the cell at bin+(lz,ly,lx).
    int mask = 0xFF;
    if (!(cc.y & 3)) mask &= 0x55;
    if (!(cc.z & 3)) mask &= 0x33;
    if (!(cc.w & 3)) mask &= 0x0F;
    int rec = (i << 8) | mask;
    int pos = atomicAdd(&counts[bin], 1);
    if (pos < CAP) {
        records[bin * CAP + pos] = rec;
    } else {
        int o = atomicAdd(ovf_n, 1);
        if (o < OVF_CAP) ovf[o] = make_int2(bin, rec);
    }
}

// One wave per output cell. Lane = (candidate slot q = lane>>3, channel quad cq = lane&7).
// Flat dependence: 8 count loads || 8 record loads || 8 predicated float4 feat loads.
__global__ __launch_bounds__(256) void k_gather_cap(const float4* __restrict__ feat4,
                                                    const int* __restrict__ counts,
                                                    const int* __restrict__ records,
                                                    const int* __restrict__ ovf_n,
                                                    const int2* __restrict__ ovf,
                                                    float4* __restrict__ out4) {
    int tid  = blockIdx.x * blockDim.x + threadIdx.x;
    int wid  = tid >> 6;             // output cell id
    int lane = threadIdx.x & 63;
    int q    = lane >> 3;            // candidate slot 0..7
    int cq   = lane & 7;             // channel quad 0..7

    int ox  = wid & (OW - 1);
    int oy  = (wid >> 5) & (OH - 1);
    int bzc = wid >> 10;             // b*OD + oz, in [0, 48)
    int b   = (bzc >= OD) ? 1 : 0;
    int oz  = bzc - b * OD;

    // level 1: bin ids + clamped counts (wave-uniform broadcast loads)
    int bins[8], cnt[8];
#pragma unroll
    for (int k = 0; k < 8; ++k) {
        const int lz = k & 1, ly = (k >> 1) & 1, lx = (k >> 2) & 1;
        int z2 = oz - lz, y2 = oy - ly, x2 = ox - lx;
        bool okbin = ((z2 | y2 | x2) >= 0);
        int bin = ((b * OD + z2) * OH + y2) * OW + x2;
        bins[k] = okbin ? bin : -1;
        int c = okbin ? counts[okbin ? bin : 0] : 0;
        cnt[k] = (c > CAP) ? CAP : c;
    }

    // level 2: records (masked lanes clamp to slot 0, discarded by predicate)
    int recs[8];
#pragma unroll
    for (int k = 0; k < 8; ++k) {
        int base = (bins[k] >= 0 ? bins[k] : 0) * CAP;
        recs[k] = records[base + ((q < cnt[k]) ? q : 0)];
    }

    // level 3: predicated feature loads + accumulate
    float4 m = make_float4(-FLT_MAX, -FLT_MAX, -FLT_MAX, -FLT_MAX);
    int any = 0;
#pragma unroll
    for (int k = 0; k < 8; ++k) {
        int rec = recs[k];
        bool ok = (q < cnt[k]) && ((rec >> k) & 1);
        if (ok) {
            float4 f = feat4[(rec >> 8) * (NC / 4) + cq];
            m.x = fmaxf(m.x, f.x); m.y = fmaxf(m.y, f.y);
            m.z = fmaxf(m.z, f.z); m.w = fmaxf(m.w, f.w);
            any = 1;
        }
    }

    // slow path: bins with 8 < count <= CAP (wave-uniform trip counts)
#pragma unroll
    for (int k = 0; k < 8; ++k) {
        for (int j0 = 8; j0 < cnt[k]; j0 += 8) {
            int j = j0 + q;
            bool ok = (j < cnt[k]);
            int rec = records[bins[k] * CAP + (ok ? j : 0)];
            ok = ok && ((rec >> k) & 1);
            if (ok) {
                float4 f = feat4[(rec >> 8) * (NC / 4) + cq];
                m.x = fmaxf(m.x, f.x); m.y = fmaxf(m.y, f.y);
                m.z = fmaxf(m.z, f.z); m.w = fmaxf(m.w, f.w);
                any = 1;
            }
        }
    }

    // overflow list (expected length 0 for this distribution; correctness net)
    int on = *ovf_n;
    if (on > 0) {
        if (on > OVF_CAP) on = OVF_CAP;
        for (int j = 0; j < on; ++j) {
            int2 e = ovf[j];
#pragma unroll
            for (int k = 0; k < 8; ++k) {
                if (e.x == bins[k] && ((e.y >> k) & 1)) {
                    float4 f = feat4[(e.y >> 8) * (NC / 4) + cq];
                    m.x = fmaxf(m.x, f.x); m.y = fmaxf(m.y, f.y);
                    m.z = fmaxf(m.z, f.z); m.w = fmaxf(m.w, f.w);
                    any = 1;
                }
            }
        }
    }

    // reduce across the 8 candidate slots (lanes differing in bits 3..5)
#pragma unroll
    for (int s = 8; s < 64; s <<= 1) {
        m.x = fmaxf(m.x, __shfl_xor(m.x, s, 64));
        m.y = fmaxf(m.y, __shfl_xor(m.y, s, 64));
        m.z = fmaxf(m.z, __shfl_xor(m.z, s, 64));
        m.w = fmaxf(m.w, __shfl_xor(m.w, s, 64));
    }
    bool active = (__ballot(any) != 0ULL);

    if (q == 0) {
        float4 z4 = make_float4(0.f, 0.f, 0.f, 0.f);
        out4[wid * (NC / 4) + cq] = active ? m : z4;
    }
}

// ================= fallback path (round-3, scan-based) ======================

__global__ void k_hist(const int* __restrict__ coors, int* __restrict__ counts, int N) {
    int i = blockIdx.x * blockDim.x + threadIdx.x;
    if (i >= N) return;
    int4 cc = reinterpret_cast<const int4*>(coors)[i];
    int bin = (((cc.x * OD + (cc.y >> 2)) * OH + (cc.z >> 2)) * OW + (cc.w >> 2));
    atomicAdd(&counts[bin], 1);
}

__global__ void k_scan(const int* __restrict__ counts,
                       int2* __restrict__ binfo,
                       int* __restrict__ cursor) {
    __shared__ int lds[SCAN_T];
    int t = threadIdx.x;
    int base = t * CHUNK;
    int s = 0;
#pragma unroll
    for (int k = 0; k < CHUNK; ++k) s += counts[base + k];
    lds[t] = s;
    __syncthreads();
    for (int d = 1; d < SCAN_T; d <<= 1) {
        int v = (t >= d) ? lds[t - d] : 0;
        __syncthreads();
        lds[t] += v;
        __syncthreads();
    }
    int excl = (t == 0) ? 0 : lds[t - 1];
    for (int k = 0; k < CHUNK; ++k) {
        int i = base + k;
        int c = counts[i];
        binfo[i] = make_int2(excl, c);
        cursor[i] = excl;
        excl += c;
    }
}

__global__ void k_place(const int* __restrict__ coors, int* __restrict__ cursor,
                        int* __restrict__ records, int N) {
    int i = blockIdx.x * blockDim.x + threadIdx.x;
    if (i >= N) return;
    int4 cc = reinterpret_cast<const int4*>(coors)[i];
    int bin = (((cc.x * OD + (cc.y >> 2)) * OH + (cc.z >> 2)) * OW + (cc.w >> 2));
    int pos = atomicAdd(&cursor[bin], 1);
    records[pos] = (i << 6) | (cc.y & 3) | ((cc.z & 3) << 2) | ((cc.w & 3) << 4);
}

__global__ __launch_bounds__(256) void k_gather(const float4* __restrict__ feat4,
                                                const int2* __restrict__ binfo,
                                                const int* __restrict__ records,
                                                float4* __restrict__ out4, int N) {
    int tid  = blockIdx.x * blockDim.x + threadIdx.x;
    int wid  = tid >> 6;
    int lane = threadIdx.x & 63;
    int q    = lane >> 3;
    int cq   = lane & 7;

    int ox  = wid & (OW - 1);
    int oy  = (wid >> 5) & (OH - 1);
    int bzc = wid >> 10;
    int b   = (bzc >= OD) ? 1 : 0;
    int oz  = bzc - b * OD;

    int2 bi[8];
#pragma unroll
    for (int k = 0; k < 8; ++k) {
        const int lz = k & 1, ly = (k >> 1) & 1, lx = (k >> 2) & 1;
        int z2 = oz - lz, y2 = oy - ly, x2 = ox - lx;
        bool okbin = ((z2 | y2 | x2) >= 0);
        int bin = ((b * OD + z2) * OH + y2) * OW + x2;
        int2 v = binfo[okbin ? bin : 0];
        if (!okbin) { v.x = N; v.y = 0; }
        bi[k] = v;
    }

    int recs[8];
#pragma unroll
    for (int k = 0; k < 8; ++k) {
        int j = (q < bi[k].y) ? q : 0;
        recs[k] = records[bi[k].x + j];
    }

    float4 m = make_float4(-FLT_MAX, -FLT_MAX, -FLT_MAX, -FLT_MAX);
    int any = 0;
#pragma unroll
    for (int k = 0; k < 8; ++k) {
        int rec = recs[k];
        bool ok = (q < bi[k].y);
        if (k & 1) ok = ok && ((rec & 3)  != 0);
        if (k & 2) ok = ok && ((rec & 12) != 0);
        if (k & 4) ok = ok && ((rec & 48) != 0);
        if (ok) {
            float4 f = feat4[(rec >> 6) * (NC / 4) + cq];
            m.x = fmaxf(m.x, f.x); m.y = fmaxf(m.y, f.y);
            m.z = fmaxf(m.z, f.z); m.w = fmaxf(m.w, f.w);
            any = 1;
        }
    }

#pragma unroll
    for (int k = 0; k < 8; ++k) {
        for (int j0 = 8; j0 < bi[k].y; j0 += 8) {
            int j = j0 + q;
            bool ok = (j < bi[k].y);
            int rec = records[bi[k].x + (ok ? j : 0)];
            if (k & 1) ok = ok && ((rec & 3)  != 0);
            if (k & 2) ok = ok && ((rec & 12) != 0);
            if (k & 4) ok = ok && ((rec & 48) != 0);
            if (ok) {
                float4 f = feat4[(rec >> 6) * (NC / 4) + cq];
                m.x = fmaxf(m.x, f.x); m.y = fmaxf(m.y, f.y);
                m.z = fmaxf(m.z, f.z); m.w = fmaxf(m.w, f.w);
                any = 1;
            }
        }
    }

#pragma unroll
    for (int s = 8; s < 64; s <<= 1) {
        m.x = fmaxf(m.x, __shfl_xor(m.x, s, 64));
        m.y = fmaxf(m.y, __shfl_xor(m.y, s, 64));
        m.z = fmaxf(m.z, __shfl_xor(m.z, s, 64));
        m.w = fmaxf(m.w, __shfl_xor(m.w, s, 64));
    }
    bool active = (__ballot(any) != 0ULL);

    if (q == 0) {
        float4 z4 = make_float4(0.f, 0.f, 0.f, 0.f);
        out4[wid * (NC / 4) + cq] = active ? m : z4;
    }
}

// ---------------- launch ----------------

extern "C" void kernel_launch(void* const* d_in, const int* in_sizes, int n_in,
                              void* d_out, int out_size, void* d_ws, size_t ws_size,
                              hipStream_t stream) {
    const float* feat  = (const float*)d_in[0];
    const int*   coors = (const int*)d_in[1];
    const int N = in_sizes[0] / NC;          // 200000
    float* out = (float*)d_out;              // 1572864 floats

    const size_t cap_ints = (size_t)NBINS + 8 + (size_t)NBINS * CAP + 2ull * OVF_CAP;
    if (ws_size >= cap_ints * sizeof(int)) {
        // fast path: memset + bin + gather
        int* counts  = (int*)d_ws;                    // NBINS
        int* ovf_n   = counts + NBINS;                // 1 (+7 pad)
        int* records = counts + NBINS + 8;            // NBINS*CAP
        int2* ovf    = (int2*)(records + NBINS * CAP);// OVF_CAP int2

        hipMemsetAsync(counts, 0, (NBINS + 8) * sizeof(int), stream);
        k_bin<<<(N + 255) / 256, 256, 0, stream>>>(coors, counts, records, ovf_n, ovf, N);
        k_gather_cap<<<(NBINS * 64) / 256, 256, 0, stream>>>(
            (const float4*)feat, counts, records, ovf_n, (const int2*)ovf, (float4*)out);
    } else {
        // fallback: scan-based (round-3) path, ~1.4 MB ws
        int*  counts  = (int*)d_ws;
        int2* binfo   = (int2*)(counts + NBINS);
        int*  cursor  = (int*)(binfo + NBINS);
        int*  records = cursor + NBINS;

        hipMemsetAsync(counts, 0, NBINS * sizeof(int), stream);
        k_hist <<<(N + 255) / 256, 256, 0, stream>>>(coors, counts, N);
        k_scan <<<1, SCAN_T, 0, stream>>>(counts, binfo, cursor);
        k_place<<<(N + 255) / 256, 256, 0, stream>>>(coors, cursor, records, N);
        k_gather<<<(NBINS * 64) / 256, 256, 0, stream>>>(
            (const float4*)feat, (const int2*)binfo, records, (float4*)out, N);
    }
}

// Round 5
// 66.309 us; speedup vs baseline: 2.6190x; 1.0321x over previous
//
#include <hip/hip_runtime.h>
#include <cfloat>
#include <cstdint>

// Problem constants (SHAPE=(96,128,128), B=2, C=32, two maxpool(K3,S2,P1) layers)
// Composed pooling: window 7, stride 4, pad 3. Output grid 2 x 24 x 32 x 32 x 32.
#define B_    2
#define OD    24
#define OH    32
#define OW    32
#define NC    32
#define NBINS (B_ * OD * OH * OW)   // 49152
#define LINE  16                    // ints per bin line: [count, rec0..rec14]
#define CAPR  15                    // records per line
#define OVF_CAP 100000
#define SCAN_T 1024
#define CHUNK  (NBINS / SCAN_T)

// ================= fast path ================================================
// ws layout (ints): lines[NBINS*16] | ovf_n[1] pad[7] | ovf[2*OVF_CAP]
// lines region is zeroed every launch; a real record always has mask bit0 set,
// so rec==0 self-rejects -> fast path needs NO count dependence.

__global__ __launch_bounds__(256) void k_bin(const int* __restrict__ coors,
                                             int* __restrict__ lines,
                                             int* __restrict__ ovf_n,
                                             int2* __restrict__ ovf, int N) {
    int i = blockIdx.x * blockDim.x + threadIdx.x;
    if (i >= N) return;
    int4 cc = reinterpret_cast<const int4*>(coors)[i];   // b, z, y, x
    int bin = (((cc.x * OD + (cc.y >> 2)) * OH + (cc.z >> 2)) * OW + (cc.w >> 2));
    // bit k (k = lz + 2*ly + 4*lx): point qualifies for cell bin+(lz,ly,lx)
    int mask = 0xFF;
    if (!(cc.y & 3)) mask &= 0x55;
    if (!(cc.z & 3)) mask &= 0x33;
    if (!(cc.w & 3)) mask &= 0x0F;
    int rec = (i << 8) | mask;   // mask bit0 always set -> rec != 0
    int pos = atomicAdd(&lines[bin * LINE], 1);
    if (pos < CAPR) {
        lines[bin * LINE + 1 + pos] = rec;
    } else {
        int o = atomicAdd(ovf_n, 1);
        if (o < OVF_CAP) ovf[o] = make_int2(bin, rec);
    }
}

// One wave per output cell. Lane = (slot q = lane>>3, channel quad cq = lane&7).
// Per bin: rec load (slot 1+q) issues immediately; feat depends only on rec.
__global__ __launch_bounds__(256) void k_gather(const float4* __restrict__ feat4,
                                                const int* __restrict__ lines,
                                                const int* __restrict__ ovf_n,
                                                const int2* __restrict__ ovf,
                                                float4* __restrict__ out4) {
    int tid  = blockIdx.x * blockDim.x + threadIdx.x;
    int wid  = tid >> 6;             // output cell id
    int lane = threadIdx.x & 63;
    int q    = lane >> 3;            // candidate slot 0..7
    int cq   = lane & 7;             // channel quad 0..7

    int ox  = wid & (OW - 1);
    int oy  = (wid >> 5) & (OH - 1);
    int bzc = wid >> 10;             // b*OD + oz, in [0, 48)
    int b   = (bzc >= OD) ? 1 : 0;
    int oz  = bzc - (b ? OD : 0);

    int bin0 = ((b * OD + oz) * OH + oy) * OW + ox;

    float4 m = make_float4(-FLT_MAX, -FLT_MAX, -FLT_MAX, -FLT_MAX);
    int any = 0;
    int bins[8];

#pragma unroll
    for (int k = 0; k < 8; ++k) {
        const int lz = k & 1, ly = (k >> 1) & 1, lx = (k >> 2) & 1;
        int z2 = oz - lz, y2 = oy - ly, x2 = ox - lx;
        if ((z2 | y2 | x2) >= 0) {                 // wave-uniform
            int bin  = bin0 - lz * (OH * OW) - ly * OW - lx;
            bins[k]  = bin;
            int base = bin * LINE;
            int cnt  = lines[base];                // parallel; slow/ovf only
            int rec  = lines[base + 1 + q];        // fast path: no cnt dep
            if ((rec >> k) & 1) {
                float4 f = feat4[(unsigned)(rec >> 8) * (NC / 4) + cq];
                m.x = fmaxf(m.x, f.x); m.y = fmaxf(m.y, f.y);
                m.z = fmaxf(m.z, f.z); m.w = fmaxf(m.w, f.w);
                any = 1;
            }
            if (cnt > 8) {                         // wave-uniform, ~2.4%/bin
                int s = 9 + q; if (s > CAPR) s = CAPR;   // dup read ok for max
                int rec2 = lines[base + s];
                if ((rec2 >> k) & 1) {
                    float4 f = feat4[(unsigned)(rec2 >> 8) * (NC / 4) + cq];
                    m.x = fmaxf(m.x, f.x); m.y = fmaxf(m.y, f.y);
                    m.z = fmaxf(m.z, f.z); m.w = fmaxf(m.w, f.w);
                    any = 1;
                }
            }
        } else {
            bins[k] = -1;
        }
    }

    // overflow list (expected empty; correctness net)
    int on = *ovf_n;
    if (on > 0) {
        if (on > OVF_CAP) on = OVF_CAP;
        for (int j = 0; j < on; ++j) {
            int2 e = ovf[j];
#pragma unroll
            for (int k = 0; k < 8; ++k) {
                if (e.x == bins[k] && ((e.y >> k) & 1)) {
                    float4 f = feat4[(unsigned)(e.y >> 8) * (NC / 4) + cq];
                    m.x = fmaxf(m.x, f.x); m.y = fmaxf(m.y, f.y);
                    m.z = fmaxf(m.z, f.z); m.w = fmaxf(m.w, f.w);
                    any = 1;
                }
            }
        }
    }

    // reduce across the 8 candidate slots (lane bits 3..5)
#pragma unroll
    for (int s = 8; s < 64; s <<= 1) {
        m.x = fmaxf(m.x, __shfl_xor(m.x, s, 64));
        m.y = fmaxf(m.y, __shfl_xor(m.y, s, 64));
        m.z = fmaxf(m.z, __shfl_xor(m.z, s, 64));
        m.w = fmaxf(m.w, __shfl_xor(m.w, s, 64));
    }
    bool active = (__ballot(any) != 0ULL);

    if (q == 0) {   // lanes 0..7 write the 32-channel row (128 B)
        float4 z4 = make_float4(0.f, 0.f, 0.f, 0.f);
        out4[wid * (NC / 4) + cq] = active ? m : z4;
    }
}

// ================= fallback path (round-3, scan-based) ======================

__global__ void k_hist(const int* __restrict__ coors, int* __restrict__ counts, int N) {
    int i = blockIdx.x * blockDim.x + threadIdx.x;
    if (i >= N) return;
    int4 cc = reinterpret_cast<const int4*>(coors)[i];
    int bin = (((cc.x * OD + (cc.y >> 2)) * OH + (cc.z >> 2)) * OW + (cc.w >> 2));
    atomicAdd(&counts[bin], 1);
}

__global__ void k_scan(const int* __restrict__ counts,
                       int2* __restrict__ binfo,
                       int* __restrict__ cursor) {
    __shared__ int lds[SCAN_T];
    int t = threadIdx.x;
    int base = t * CHUNK;
    int s = 0;
#pragma unroll
    for (int k = 0; k < CHUNK; ++k) s += counts[base + k];
    lds[t] = s;
    __syncthreads();
    for (int d = 1; d < SCAN_T; d <<= 1) {
        int v = (t >= d) ? lds[t - d] : 0;
        __syncthreads();
        lds[t] += v;
        __syncthreads();
    }
    int excl = (t == 0) ? 0 : lds[t - 1];
    for (int k = 0; k < CHUNK; ++k) {
        int i = base + k;
        int c = counts[i];
        binfo[i] = make_int2(excl, c);
        cursor[i] = excl;
        excl += c;
    }
}

__global__ void k_place(const int* __restrict__ coors, int* __restrict__ cursor,
                        int* __restrict__ records, int N) {
    int i = blockIdx.x * blockDim.x + threadIdx.x;
    if (i >= N) return;
    int4 cc = reinterpret_cast<const int4*>(coors)[i];
    int bin = (((cc.x * OD + (cc.y >> 2)) * OH + (cc.z >> 2)) * OW + (cc.w >> 2));
    int pos = atomicAdd(&cursor[bin], 1);
    records[pos] = (i << 6) | (cc.y & 3) | ((cc.z & 3) << 2) | ((cc.w & 3) << 4);
}

__global__ __launch_bounds__(256) void k_gather_fb(const float4* __restrict__ feat4,
                                                   const int2* __restrict__ binfo,
                                                   const int* __restrict__ records,
                                                   float4* __restrict__ out4, int N) {
    int tid  = blockIdx.x * blockDim.x + threadIdx.x;
    int wid  = tid >> 6;
    int lane = threadIdx.x & 63;
    int q    = lane >> 3;
    int cq   = lane & 7;

    int ox  = wid & (OW - 1);
    int oy  = (wid >> 5) & (OH - 1);
    int bzc = wid >> 10;
    int b   = (bzc >= OD) ? 1 : 0;
    int oz  = bzc - b * OD;

    int2 bi[8];
#pragma unroll
    for (int k = 0; k < 8; ++k) {
        const int lz = k & 1, ly = (k >> 1) & 1, lx = (k >> 2) & 1;
        int z2 = oz - lz, y2 = oy - ly, x2 = ox - lx;
        bool okbin = ((z2 | y2 | x2) >= 0);
        int bin = ((b * OD + z2) * OH + y2) * OW + x2;
        int2 v = binfo[okbin ? bin : 0];
        if (!okbin) { v.x = N; v.y = 0; }
        bi[k] = v;
    }

    int recs[8];
#pragma unroll
    for (int k = 0; k < 8; ++k) {
        int j = (q < bi[k].y) ? q : 0;
        recs[k] = records[bi[k].x + j];
    }

    float4 m = make_float4(-FLT_MAX, -FLT_MAX, -FLT_MAX, -FLT_MAX);
    int any = 0;
#pragma unroll
    for (int k = 0; k < 8; ++k) {
        int rec = recs[k];
        bool ok = (q < bi[k].y);
        if (k & 1) ok = ok && ((rec & 3)  != 0);
        if (k & 2) ok = ok && ((rec & 12) != 0);
        if (k & 4) ok = ok && ((rec & 48) != 0);
        if (ok) {
            float4 f = feat4[(rec >> 6) * (NC / 4) + cq];
            m.x = fmaxf(m.x, f.x); m.y = fmaxf(m.y, f.y);
            m.z = fmaxf(m.z, f.z); m.w = fmaxf(m.w, f.w);
            any = 1;
        }
    }

#pragma unroll
    for (int k = 0; k < 8; ++k) {
        for (int j0 = 8; j0 < bi[k].y; j0 += 8) {
            int j = j0 + q;
            bool ok = (j < bi[k].y);
            int rec = records[bi[k].x + (ok ? j : 0)];
            if (k & 1) ok = ok && ((rec & 3)  != 0);
            if (k & 2) ok = ok && ((rec & 12) != 0);
            if (k & 4) ok = ok && ((rec & 48) != 0);
            if (ok) {
                float4 f = feat4[(rec >> 6) * (NC / 4) + cq];
                m.x = fmaxf(m.x, f.x); m.y = fmaxf(m.y, f.y);
                m.z = fmaxf(m.z, f.z); m.w = fmaxf(m.w, f.w);
                any = 1;
            }
        }
    }

#pragma unroll
    for (int s = 8; s < 64; s <<= 1) {
        m.x = fmaxf(m.x, __shfl_xor(m.x, s, 64));
        m.y = fmaxf(m.y, __shfl_xor(m.y, s, 64));
        m.z = fmaxf(m.z, __shfl_xor(m.z, s, 64));
        m.w = fmaxf(m.w, __shfl_xor(m.w, s, 64));
    }
    bool active = (__ballot(any) != 0ULL);

    if (q == 0) {
        float4 z4 = make_float4(0.f, 0.f, 0.f, 0.f);
        out4[wid * (NC / 4) + cq] = active ? m : z4;
    }
}

// ---------------- launch ----------------

extern "C" void kernel_launch(void* const* d_in, const int* in_sizes, int n_in,
                              void* d_out, int out_size, void* d_ws, size_t ws_size,
                              hipStream_t stream) {
    const float* feat  = (const float*)d_in[0];
    const int*   coors = (const int*)d_in[1];
    const int N = in_sizes[0] / NC;          // 200000
    float* out = (float*)d_out;              // 1572864 floats

    const size_t fast_ints = (size_t)NBINS * LINE + 8 + 2ull * OVF_CAP;
    if (ws_size >= fast_ints * sizeof(int)) {
        int*  lines = (int*)d_ws;                       // NBINS*16
        int*  ovf_n = lines + NBINS * LINE;             // 1 (+7 pad)
        int2* ovf   = (int2*)(ovf_n + 8);               // OVF_CAP int2

        hipMemsetAsync(lines, 0, ((size_t)NBINS * LINE + 8) * sizeof(int), stream);
        k_bin<<<(N + 255) / 256, 256, 0, stream>>>(coors, lines, ovf_n, ovf, N);
        k_gather<<<(NBINS * 64) / 256, 256, 0, stream>>>(
            (const float4*)feat, lines, ovf_n, (const int2*)ovf, (float4*)out);
    } else {
        // fallback: scan-based path, ~1.4 MB ws
        int*  counts  = (int*)d_ws;
        int2* binfo   = (int2*)(counts + NBINS);
        int*  cursor  = (int*)(binfo + NBINS);
        int*  records = cursor + NBINS;

        hipMemsetAsync(counts, 0, NBINS * sizeof(int), stream);
        k_hist <<<(N + 255) / 256, 256, 0, stream>>>(coors, counts, N);
        k_scan <<<1, SCAN_T, 0, stream>>>(counts, binfo, cursor);
        k_place<<<(N + 255) / 256, 256, 0, stream>>>(coors, cursor, records, N);
        k_gather_fb<<<(NBINS * 64) / 256, 256, 0, stream>>>(
            (const float4*)feat, (const int2*)binfo, records, (float4*)out, N);
    }
}

// Round 6
// 46.519 us; speedup vs baseline: 3.7331x; 1.4254x over previous
//
#include <hip/hip_runtime.h>
#include <cfloat>
#include <cstdint>

// Problem constants (SHAPE=(96,128,128), B=2, C=32, two maxpool(K3,S2,P1) layers)
// Composed pooling: window 7, stride 4, pad 3. Output grid 2 x 24 x 32 x 32 x 32.
#define B_    2
#define OD    24
#define OH    32
#define OW    32
#define NC    32
#define NBINS (B_ * OD * OH * OW)   // 49152
#define LINE  16                    // ints per bin line: [count, rec0..rec14]
#define CAPR  15
#define OVF_CAP 100000
#define SCAN_T 1024
#define CHUNK  (NBINS / SCAN_T)

// tile geometry: 4 x 4 x 2 output cells per workgroup
#define TZ 4
#define TY 4
#define TX 2
#define TCELLS (TZ*TY*TX)           // 32
#define NTZ (OD/TZ)                 // 6
#define NTY (OH/TY)                 // 8
#define NTX (OW/TX)                 // 16
#define NTILES (B_*NTZ*NTY*NTX)     // 1536
#define NBZ (TZ+1)                  // 5
#define NBY (TY+1)                  // 5
#define NBX (TX+1)                  // 3
#define NB  (NBZ*NBY*NBX)           // 75 bins per tile
#define LIST_CAP 1280
#define DUMP (TCELLS*NC)            // dump row base (branchless rejected atomics)

// ---------------- prologue ----------------

__global__ void k_zero(int* __restrict__ lines, int* __restrict__ ovf_n) {
    int i = blockIdx.x * blockDim.x + threadIdx.x;
    if (i < NBINS) lines[i * LINE] = 0;
    if (i == 0) *ovf_n = 0;
}

__global__ __launch_bounds__(256) void k_bin(const int* __restrict__ coors,
                                             int* __restrict__ lines,
                                             int* __restrict__ ovf_n,
                                             int2* __restrict__ ovf, int N) {
    int i = blockIdx.x * blockDim.x + threadIdx.x;
    if (i >= N) return;
    int4 cc = reinterpret_cast<const int4*>(coors)[i];   // b, z, y, x
    int bin = (((cc.x * OD + (cc.y >> 2)) * OH + (cc.z >> 2)) * OW + (cc.w >> 2));
    // bit k (k = lz + 2*ly + 4*lx): point qualifies for cell bin+(lz,ly,lx)
    int mask = 0xFF;
    if (!(cc.y & 3)) mask &= 0x55;
    if (!(cc.z & 3)) mask &= 0x33;
    if (!(cc.w & 3)) mask &= 0x0F;
    int rec = (i << 8) | mask;   // mask bit0 always set -> rec != 0
    int pos = atomicAdd(&lines[bin * LINE], 1);
    if (pos < CAPR) {
        lines[bin * LINE + 1 + pos] = rec;
    } else {
        int o = atomicAdd(ovf_n, 1);
        if (o < OVF_CAP) ovf[o] = make_int2(bin, rec);
    }
}

// ---------------- tile gather-scatter ----------------
// Monotone float->uint transform: order-preserving for all non-NaN floats,
// transform(f) >= 0x00800000 > 0 for all finite f, so 0 == "never touched".
__device__ __forceinline__ unsigned xform(float f) {
    unsigned u = __float_as_uint(f);
    return u ^ ((unsigned)((int)u >> 31) | 0x80000000u);
}
__device__ __forceinline__ float unxform(unsigned t) {
    return (t == 0u) ? 0.0f
           : __uint_as_float((t >> 31) ? (t ^ 0x80000000u) : ~t);
}

__global__ __launch_bounds__(512) void k_tile(const float* __restrict__ feat,
                                              const int* __restrict__ lines,
                                              const int* __restrict__ ovf_n,
                                              const int2* __restrict__ ovf,
                                              float4* __restrict__ out4) {
    __shared__ unsigned sm_out[TCELLS * NC + 32];   // + 32-word dump row
    __shared__ int2 list[LIST_CAP];
    __shared__ int sm_cursor;

    const int tid = threadIdx.x;
    int bid = blockIdx.x;
    int b  = (bid >= NTZ * NTY * NTX) ? 1 : 0;
    int r  = bid - b * (NTZ * NTY * NTX);
    int ti = r >> 7;            // / (NTY*NTX) = 128
    int rr = r & 127;
    int tj = rr >> 4;           // / NTX = 16
    int tl = rr & 15;
    const int tz0 = ti * TZ, ty0 = tj * TY, tx0 = tl * TX;

    if (tid == 0) sm_cursor = 0;
    for (int v = tid; v < TCELLS * NC + 32; v += 512) sm_out[v] = 0u;
    __syncthreads();

    // ---- build compact entry list: (idx<<8 | tile-clipped mask, base cell) ----
    if (tid < NB) {
        int rz  = tid / (NBY * NBX);
        int rem = tid - rz * (NBY * NBX);
        int ry  = rem / NBX;
        int rx  = rem - ry * NBX;
        int bz = tz0 - 1 + rz, by = ty0 - 1 + ry, bx = tx0 - 1 + rx;
        if ((bz | by | bx) >= 0) {            // high side always in-grid
            int bin = ((b * OD + bz) * OH + by) * OW + bx;
            const int4* lp = (const int4*)(lines + bin * LINE);
            int4 q0 = lp[0], q1 = lp[1], q2 = lp[2], q3 = lp[3];
            int rbuf[16];
            *(int4*)&rbuf[0]  = q0; *(int4*)&rbuf[4]  = q1;
            *(int4*)&rbuf[8]  = q2; *(int4*)&rbuf[12] = q3;
            int cnt = rbuf[0]; if (cnt > CAPR) cnt = CAPR;
            int bi = rz - 1, bj = ry - 1, bl = rx - 1;
            int vm = 0xFF;                    // tile-validity mask per k
            if (bi < 0) vm &= 0xAA;  if (bi > TZ - 2) vm &= 0x55;
            if (bj < 0) vm &= 0xCC;  if (bj > TY - 2) vm &= 0x33;
            if (bl < 0) vm &= 0xF0;  if (bl > TX - 2) vm &= 0x0F;
            int cb = bi * (TY * TX) + bj * TX + bl;
#pragma unroll
            for (int rs = 0; rs < CAPR; ++rs) {
                if (rs < cnt) {
                    int rec = rbuf[rs + 1];
                    int fm = rec & vm & 0xFF;
                    if (fm) {
                        int pos = atomicAdd(&sm_cursor, 1);
                        if (pos < LIST_CAP)
                            list[pos] = make_int2((rec & ~0xFF) | fm, cb);
                    }
                }
            }
        }
    }
    // ---- overflow net (expected empty) ----
    int on = *ovf_n;
    if (on > 0 && tid == 0) {
        if (on > OVF_CAP) on = OVF_CAP;
        for (int e = 0; e < on; ++e) {
            int2 ov = ovf[e];
            int bx = ov.x & (OW - 1);
            int by = (ov.x >> 5) & (OH - 1);
            int rest = ov.x >> 10;            // b*OD + bz
            int bb = (rest >= OD) ? 1 : 0;
            int bz = rest - bb * OD;
            if (bb != b) continue;
            int rz = bz - (tz0 - 1), ry = by - (ty0 - 1), rx = bx - (tx0 - 1);
            if (rz < 0 || rz >= NBZ || ry < 0 || ry >= NBY || rx < 0 || rx >= NBX) continue;
            int bi = rz - 1, bj = ry - 1, bl = rx - 1;
            int vm = 0xFF;
            if (bi < 0) vm &= 0xAA;  if (bi > TZ - 2) vm &= 0x55;
            if (bj < 0) vm &= 0xCC;  if (bj > TY - 2) vm &= 0x33;
            if (bl < 0) vm &= 0xF0;  if (bl > TX - 2) vm &= 0x0F;
            int fm = ov.y & vm & 0xFF;
            if (fm) {
                int pos = atomicAdd(&sm_cursor, 1);
                if (pos < LIST_CAP)
                    list[pos] = make_int2((ov.y & ~0xFF) | fm,
                                          bi * (TY * TX) + bj * TX + bl);
            }
        }
    }
    __syncthreads();
    int total = sm_cursor; if (total > LIST_CAP) total = LIST_CAP;

    // ---- main loop: thread = (slot s, channel c); 2 entries per slot/round ----
    const int s = tid >> 5;      // 16 slots
    const int c = tid & 31;

    for (int j = s; j < total; j += 32) {
        int2 e0 = list[j];
        bool h1 = (j + 16) < total;
        int2 e1 = h1 ? list[j + 16] : make_int2(0, 0);   // fm=0 -> no-op
        float f0 = feat[(((unsigned)e0.x) >> 8) * NC + c];
        float f1 = feat[(((unsigned)e1.x) >> 8) * NC + c];
        unsigned t0 = xform(f0);
        unsigned t1 = xform(f1);
        int fm0 = e0.x & 0xFF, cb0 = e0.y;
        int fm1 = e1.x & 0xFF, cb1 = e1.y;
#pragma unroll
        for (int k = 0; k < 8; ++k) {
            const int koff = (k & 1) * (TY * TX) + ((k >> 1) & 1) * TX + ((k >> 2) & 1);
            int a0 = ((fm0 >> k) & 1) ? (cb0 + koff) * NC : DUMP;
            atomicMax(&sm_out[a0 + c], t0);
            int a1 = ((fm1 >> k) & 1) ? (cb1 + koff) * NC : DUMP;
            atomicMax(&sm_out[a1 + c], t1);
        }
    }
    __syncthreads();

    // ---- epilogue: 32 cells x 8 float4, dense coalesced stores ----
    if (tid < TCELLS * NC / 4) {
        int cell = tid >> 3, quad = tid & 7;
        int i = cell >> 3, jj = (cell >> 1) & 3, l = cell & 1;
        uint4 uv = *(const uint4*)&sm_out[cell * NC + quad * 4];
        float4 o;
        o.x = unxform(uv.x); o.y = unxform(uv.y);
        o.z = unxform(uv.z); o.w = unxform(uv.w);
        out4[(((b * OD + tz0 + i) * OH + (ty0 + jj)) * OW + (tx0 + l)) * (NC / 4) + quad] = o;
    }
}

// ================= fallback path (scan-based, small ws) =====================

__global__ void k_hist(const int* __restrict__ coors, int* __restrict__ counts, int N) {
    int i = blockIdx.x * blockDim.x + threadIdx.x;
    if (i >= N) return;
    int4 cc = reinterpret_cast<const int4*>(coors)[i];
    int bin = (((cc.x * OD + (cc.y >> 2)) * OH + (cc.z >> 2)) * OW + (cc.w >> 2));
    atomicAdd(&counts[bin], 1);
}

__global__ void k_scan(const int* __restrict__ counts,
                       int2* __restrict__ binfo,
                       int* __restrict__ cursor) {
    __shared__ int lds[SCAN_T];
    int t = threadIdx.x;
    int base = t * CHUNK;
    int s = 0;
#pragma unroll
    for (int k = 0; k < CHUNK; ++k) s += counts[base + k];
    lds[t] = s;
    __syncthreads();
    for (int d = 1; d < SCAN_T; d <<= 1) {
        int v = (t >= d) ? lds[t - d] : 0;
        __syncthreads();
        lds[t] += v;
        __syncthreads();
    }
    int excl = (t == 0) ? 0 : lds[t - 1];
    for (int k = 0; k < CHUNK; ++k) {
        int i = base + k;
        int c = counts[i];
        binfo[i] = make_int2(excl, c);
        cursor[i] = excl;
        excl += c;
    }
}

__global__ void k_place(const int* __restrict__ coors, int* __restrict__ cursor,
                        int* __restrict__ records, int N) {
    int i = blockIdx.x * blockDim.x + threadIdx.x;
    if (i >= N) return;
    int4 cc = reinterpret_cast<const int4*>(coors)[i];
    int bin = (((cc.x * OD + (cc.y >> 2)) * OH + (cc.z >> 2)) * OW + (cc.w >> 2));
    int pos = atomicAdd(&cursor[bin], 1);
    records[pos] = (i << 6) | (cc.y & 3) | ((cc.z & 3) << 2) | ((cc.w & 3) << 4);
}

__global__ __launch_bounds__(256) void k_gather_fb(const float4* __restrict__ feat4,
                                                   const int2* __restrict__ binfo,
                                                   const int* __restrict__ records,
                                                   float4* __restrict__ out4, int N) {
    int tid  = blockIdx.x * blockDim.x + threadIdx.x;
    int wid  = tid >> 6;
    int lane = threadIdx.x & 63;
    int q    = lane >> 3;
    int cq   = lane & 7;

    int ox  = wid & (OW - 1);
    int oy  = (wid >> 5) & (OH - 1);
    int bzc = wid >> 10;
    int b   = (bzc >= OD) ? 1 : 0;
    int oz  = bzc - b * OD;

    int2 bi[8];
#pragma unroll
    for (int k = 0; k < 8; ++k) {
        const int lz = k & 1, ly = (k >> 1) & 1, lx = (k >> 2) & 1;
        int z2 = oz - lz, y2 = oy - ly, x2 = ox - lx;
        bool okbin = ((z2 | y2 | x2) >= 0);
        int bin = ((b * OD + z2) * OH + y2) * OW + x2;
        int2 v = binfo[okbin ? bin : 0];
        if (!okbin) { v.x = N; v.y = 0; }
        bi[k] = v;
    }

    int recs[8];
#pragma unroll
    for (int k = 0; k < 8; ++k) {
        int j = (q < bi[k].y) ? q : 0;
        recs[k] = records[bi[k].x + j];
    }

    float4 m = make_float4(-FLT_MAX, -FLT_MAX, -FLT_MAX, -FLT_MAX);
    int any = 0;
#pragma unroll
    for (int k = 0; k < 8; ++k) {
        int rec = recs[k];
        bool ok = (q < bi[k].y);
        if (k & 1) ok = ok && ((rec & 3)  != 0);
        if (k & 2) ok = ok && ((rec & 12) != 0);
        if (k & 4) ok = ok && ((rec & 48) != 0);
        if (ok) {
            float4 f = feat4[(rec >> 6) * (NC / 4) + cq];
            m.x = fmaxf(m.x, f.x); m.y = fmaxf(m.y, f.y);
            m.z = fmaxf(m.z, f.z); m.w = fmaxf(m.w, f.w);
            any = 1;
        }
    }

#pragma unroll
    for (int k = 0; k < 8; ++k) {
        for (int j0 = 8; j0 < bi[k].y; j0 += 8) {
            int j = j0 + q;
            bool ok = (j < bi[k].y);
            int rec = records[bi[k].x + (ok ? j : 0)];
            if (k & 1) ok = ok && ((rec & 3)  != 0);
            if (k & 2) ok = ok && ((rec & 12) != 0);
            if (k & 4) ok = ok && ((rec & 48) != 0);
            if (ok) {
                float4 f = feat4[(rec >> 6) * (NC / 4) + cq];
                m.x = fmaxf(m.x, f.x); m.y = fmaxf(m.y, f.y);
                m.z = fmaxf(m.z, f.z); m.w = fmaxf(m.w, f.w);
                any = 1;
            }
        }
    }

#pragma unroll
    for (int s = 8; s < 64; s <<= 1) {
        m.x = fmaxf(m.x, __shfl_xor(m.x, s, 64));
        m.y = fmaxf(m.y, __shfl_xor(m.y, s, 64));
        m.z = fmaxf(m.z, __shfl_xor(m.z, s, 64));
        m.w = fmaxf(m.w, __shfl_xor(m.w, s, 64));
    }
    bool active = (__ballot(any) != 0ULL);

    if (q == 0) {
        float4 z4 = make_float4(0.f, 0.f, 0.f, 0.f);
        out4[wid * (NC / 4) + cq] = active ? m : z4;
    }
}

// ---------------- launch ----------------

extern "C" void kernel_launch(void* const* d_in, const int* in_sizes, int n_in,
                              void* d_out, int out_size, void* d_ws, size_t ws_size,
                              hipStream_t stream) {
    const float* feat  = (const float*)d_in[0];
    const int*   coors = (const int*)d_in[1];
    const int N = in_sizes[0] / NC;          // 200000
    float* out = (float*)d_out;              // 1572864 floats

    const size_t fast_ints = (size_t)NBINS * LINE + 8 + 2ull * OVF_CAP;
    if (ws_size >= fast_ints * sizeof(int)) {
        int*  lines = (int*)d_ws;                       // NBINS*16
        int*  ovf_n = lines + NBINS * LINE;             // 1 (+7 pad)
        int2* ovf   = (int2*)(ovf_n + 8);               // OVF_CAP int2

        k_zero<<<(NBINS + 255) / 256, 256, 0, stream>>>(lines, ovf_n);
        k_bin<<<(N + 255) / 256, 256, 0, stream>>>(coors, lines, ovf_n, ovf, N);
        k_tile<<<NTILES, 512, 0, stream>>>(feat, lines, ovf_n, (const int2*)ovf,
                                           (float4*)out);
    } else {
        // fallback: scan-based path, ~1.6 MB ws
        int*  counts  = (int*)d_ws;
        int2* binfo   = (int2*)(counts + NBINS);
        int*  cursor  = (int*)(binfo + NBINS);
        int*  records = cursor + NBINS;

        hipMemsetAsync(counts, 0, NBINS * sizeof(int), stream);
        k_hist <<<(N + 255) / 256, 256, 0, stream>>>(coors, counts, N);
        k_scan <<<1, SCAN_T, 0, stream>>>(counts, binfo, cursor);
        k_place<<<(N + 255) / 256, 256, 0, stream>>>(coors, cursor, records, N);
        k_gather_fb<<<(NBINS * 64) / 256, 256, 0, stream>>>(
            (const float4*)feat, (const int2*)binfo, records, (float4*)out, N);
    }
}